// Round 6
// baseline (427.957 us; speedup 1.0000x reference)
//
#include <hip/hip_runtime.h>

#define NNODE 50000
#define NEDGE 800000
#define NB1   196        // ceil(50000/256)

// ---------------- CSR build: count, scan, fill ----------------

__global__ void k_count(const int* __restrict__ dst, int* __restrict__ cnt) {
    int i = blockIdx.x * 256 + threadIdx.x;
    if (i < NEDGE) atomicAdd(&cnt[dst[i]], 1);
}

__global__ void k_scan1(const int* __restrict__ cnt, int* __restrict__ incl, int* __restrict__ bsum) {
    __shared__ int s[256];
    int i = blockIdx.x * 256 + threadIdx.x;
    int v = (i < NNODE) ? cnt[i] : 0;
    s[threadIdx.x] = v;
    __syncthreads();
#pragma unroll
    for (int off = 1; off < 256; off <<= 1) {
        int t = (threadIdx.x >= off) ? s[threadIdx.x - off] : 0;
        __syncthreads();
        s[threadIdx.x] += t;
        __syncthreads();
    }
    if (i < NNODE) incl[i] = s[threadIdx.x];
    if (threadIdx.x == 255) bsum[blockIdx.x] = s[255];
}

__global__ void k_scan2(int* __restrict__ bsum) {
    __shared__ int s[256];
    int v = (threadIdx.x < NB1) ? bsum[threadIdx.x] : 0;
    s[threadIdx.x] = v;
    __syncthreads();
#pragma unroll
    for (int off = 1; off < 256; off <<= 1) {
        int t = (threadIdx.x >= off) ? s[threadIdx.x - off] : 0;
        __syncthreads();
        s[threadIdx.x] += t;
        __syncthreads();
    }
    if (threadIdx.x < NB1) bsum[threadIdx.x] = s[threadIdx.x];
}

__global__ void k_scan3(const int* __restrict__ incl, const int* __restrict__ bsum,
                        const int* __restrict__ cnt, int* __restrict__ rowstart,
                        int* __restrict__ cursor, float* __restrict__ dinv) {
    int i = blockIdx.x * 256 + threadIdx.x;
    if (i >= NNODE) return;
    int boff = (blockIdx.x == 0) ? 0 : bsum[blockIdx.x - 1];
    int inc = incl[i] + boff;
    rowstart[i + 1] = inc;
    cursor[i] = inc - cnt[i];
    dinv[i] = rsqrtf((float)cnt[i] + 1.0f);   // +1 self loop
    if (i == 0) rowstart[0] = 0;
}

__global__ void k_fill(const int* __restrict__ src, const int* __restrict__ dst,
                       int* __restrict__ cursor, int* __restrict__ csr_src) {
    int e = blockIdx.x * 256 + threadIdx.x;
    if (e >= NEDGE) return;
    int d = dst[e];
    int pos = atomicAdd(&cursor[d], 1);
    csr_src[pos] = src[e];
}

// ---------------- GEMM + prescale by dinv[row] ----------------
// Wave = 64 cols (lane=col), 8 rows/thread, 32 rows/block.
// W stored TRANSPOSED in LDS with XOR swizzle (float-idx: k ^ ((c&7)<<2)),
// read as ds_read_b128 (2-way bank alias = free). Software-pipelined:
// next w + next x loaded while computing current 32 FMAs.

template<int FIN, int FOUT>
__launch_bounds__(256)
__global__ void k_gemm_prescale(const float* __restrict__ X, const float* __restrict__ W,
                                const float* __restrict__ dinv, float* __restrict__ XWs) {
    constexpr int ROWS = 8;
    __shared__ float Wt[64 * FIN];   // [col][k], swizzled

    // stage W^T (zeros for cols >= FOUT)
    for (int idx = threadIdx.x; idx < 64 * FIN; idx += 256) {
        int k = idx >> 6;
        int c = idx & 63;
        float v = (c < FOUT) ? W[k * FOUT + c] : 0.0f;   // coalesced global read
        Wt[c * FIN + (k ^ ((c & 7) << 2))] = v;
    }
    __syncthreads();

    int wid  = threadIdx.x >> 6;
    int lane = threadIdx.x & 63;
    int base = blockIdx.x * (4 * ROWS) + wid * ROWS;

    const float4* xp[ROWS];
    float dv[ROWS];
#pragma unroll
    for (int i = 0; i < ROWS; ++i) {
        int r = base + i; if (r >= NNODE) r = NNODE - 1;   // clamp tail
        xp[i] = (const float4*)(X + (size_t)r * FIN);
        dv[i] = dinv[r];
    }

    const float* wrow = &Wt[lane * FIN];
    const int swz = (lane & 7) << 2;
    constexpr int NIT = FIN / 4;

    float4 xc[ROWS], xn[ROWS];
    float4 wc, wn;
#pragma unroll
    for (int i = 0; i < ROWS; ++i) xc[i] = xp[i][0];
    wc = *(const float4*)&wrow[0 ^ swz];

    float acc[ROWS];
#pragma unroll
    for (int i = 0; i < ROWS; ++i) acc[i] = 0.0f;

    for (int k4 = 0; k4 < NIT; ++k4) {
        if (k4 + 1 < NIT) {
#pragma unroll
            for (int i = 0; i < ROWS; ++i) xn[i] = xp[i][k4 + 1];
            wn = *(const float4*)&wrow[((k4 + 1) << 2) ^ swz];
        }
#pragma unroll
        for (int i = 0; i < ROWS; ++i) {
            acc[i] = fmaf(xc[i].x, wc.x, acc[i]);
            acc[i] = fmaf(xc[i].y, wc.y, acc[i]);
            acc[i] = fmaf(xc[i].z, wc.z, acc[i]);
            acc[i] = fmaf(xc[i].w, wc.w, acc[i]);
        }
        if (k4 + 1 < NIT) {
#pragma unroll
            for (int i = 0; i < ROWS; ++i) xc[i] = xn[i];
            wc = wn;
        }
    }

    if (lane < FOUT) {
#pragma unroll
        for (int i = 0; i < ROWS; ++i) {
            int r = base + i;
            if (r < NNODE) XWs[(size_t)r * FOUT + lane] = acc[i] * dv[i];
        }
    }
}

// ---------------- CSR aggregate + finalize ----------------
// out[d][f] = act(dinv[d] * (XWs[d][f] + sum_{e in row d} XWs[src_e][f]) + b[f])
// one wave per destination node; lane = feature; gather unrolled x8 for MLP.

template<int F, bool RELU>
__launch_bounds__(256)
__global__ void k_aggregate(const float* __restrict__ XWs, const int* __restrict__ rowstart,
                            const int* __restrict__ csr_src, const float* __restrict__ dinv,
                            const float* __restrict__ b, float* __restrict__ out) {
    int wid  = threadIdx.x >> 6;
    int lane = threadIdx.x & 63;
    int d = blockIdx.x * 4 + wid;
    if (d >= NNODE) return;

    int beg = rowstart[d];
    int end = rowstart[d + 1];

    float acc = (lane < F) ? XWs[(size_t)d * F + lane] : 0.0f;  // self loop

    for (int base = beg; base < end; base += 64) {
        int idx = base + lane;
        int sv = (idx < end) ? csr_src[idx] : 0;   // coalesced edge-list load
        int nv = min(64, end - base);
        int j = 0;
        for (; j + 8 <= nv; j += 8) {
            int s0 = __shfl(sv, j + 0), s1 = __shfl(sv, j + 1);
            int s2 = __shfl(sv, j + 2), s3 = __shfl(sv, j + 3);
            int s4 = __shfl(sv, j + 4), s5 = __shfl(sv, j + 5);
            int s6 = __shfl(sv, j + 6), s7 = __shfl(sv, j + 7);
            float v0 = XWs[(size_t)s0 * F + lane];
            float v1 = XWs[(size_t)s1 * F + lane];
            float v2 = XWs[(size_t)s2 * F + lane];
            float v3 = XWs[(size_t)s3 * F + lane];
            float v4 = XWs[(size_t)s4 * F + lane];
            float v5 = XWs[(size_t)s5 * F + lane];
            float v6 = XWs[(size_t)s6 * F + lane];
            float v7 = XWs[(size_t)s7 * F + lane];
            acc += v0; acc += v1; acc += v2; acc += v3;
            acc += v4; acc += v5; acc += v6; acc += v7;
        }
        for (; j + 4 <= nv; j += 4) {
            int s0 = __shfl(sv, j + 0), s1 = __shfl(sv, j + 1);
            int s2 = __shfl(sv, j + 2), s3 = __shfl(sv, j + 3);
            float v0 = XWs[(size_t)s0 * F + lane];
            float v1 = XWs[(size_t)s1 * F + lane];
            float v2 = XWs[(size_t)s2 * F + lane];
            float v3 = XWs[(size_t)s3 * F + lane];
            acc += v0; acc += v1; acc += v2; acc += v3;
        }
        for (; j < nv; ++j) {
            int s = __shfl(sv, j);
            acc += XWs[(size_t)s * F + lane];
        }
    }

    if (lane < F) {
        float v = fmaf(acc, dinv[d], b[lane]);
        out[(size_t)d * F + lane] = RELU ? fmaxf(v, 0.0f) : v;
    }
}

extern "C" void kernel_launch(void* const* d_in, const int* in_sizes, int n_in,
                              void* d_out, int out_size, void* d_ws, size_t ws_size,
                              hipStream_t stream) {
    const float* x  = (const float*)d_in[0];
    const int*   ei = (const int*)d_in[1];
    const float* W1 = (const float*)d_in[2];
    const float* b1 = (const float*)d_in[3];
    const float* W2 = (const float*)d_in[4];
    const float* b2 = (const float*)d_in[5];
    const float* W3 = (const float*)d_in[6];
    const float* b3 = (const float*)d_in[7];
    float* out = (float*)d_out;

    const int* src = ei;
    const int* dst = ei + NEDGE;

    char* p = (char*)d_ws;
    auto alloc = [&](size_t bytes) { char* r = p; p += (bytes + 255) & ~size_t(255); return r; };
    int*   cnt      = (int*)  alloc(NNODE * 4);
    int*   incl     = (int*)  alloc(NNODE * 4);
    int*   bsum     = (int*)  alloc(256 * 4);
    int*   rowstart = (int*)  alloc((NNODE + 1) * 4);
    int*   cursor   = (int*)  alloc(NNODE * 4);
    int*   csr_src  = (int*)  alloc(NEDGE * 4);
    float* dinv     = (float*)alloc(NNODE * 4);
    float* XWs      = (float*)alloc((size_t)NNODE * 64 * 4 + 256);
    float* H1       = (float*)alloc((size_t)NNODE * 64 * 4);
    float* H2       = (float*)alloc((size_t)NNODE * 64 * 4);

    const int B = 256;
    const int gN    = NB1;                        // 196
    const int gE    = (NEDGE + B - 1) / B;        // 3125
    const int gGemm = (NNODE + 31) / 32;          // 1563 (32 rows/block)
    const int gAgg  = (NNODE + 3) / 4;            // 12500

    // CSR build + norm
    hipMemsetAsync(cnt, 0, NNODE * 4, stream);
    k_count<<<gE, B, 0, stream>>>(dst, cnt);
    k_scan1<<<gN, B, 0, stream>>>(cnt, incl, bsum);
    k_scan2<<<1,  B, 0, stream>>>(bsum);
    k_scan3<<<gN, B, 0, stream>>>(incl, bsum, cnt, rowstart, cursor, dinv);
    k_fill <<<gE, B, 0, stream>>>(src, dst, cursor, csr_src);

    // layer 1: 128 -> 64, relu
    k_gemm_prescale<128, 64><<<gGemm, B, 0, stream>>>(x, W1, dinv, XWs);
    k_aggregate<64, true><<<gAgg, B, 0, stream>>>(XWs, rowstart, csr_src, dinv, b1, H1);

    // layer 2: 64 -> 64, relu
    k_gemm_prescale<64, 64><<<gGemm, B, 0, stream>>>(H1, W2, dinv, XWs);
    k_aggregate<64, true><<<gAgg, B, 0, stream>>>(XWs, rowstart, csr_src, dinv, b2, H2);

    // layer 3: 64 -> 40, no act
    k_gemm_prescale<64, 40><<<gGemm, B, 0, stream>>>(H2, W3, dinv, XWs);
    k_aggregate<40, false><<<gAgg, B, 0, stream>>>(XWs, rowstart, csr_src, dinv, b3, out);
}

// Round 7
// 253.329 us; speedup vs baseline: 1.6893x; 1.6893x over previous
//
#include <hip/hip_runtime.h>

#define NNODE 50000
#define NEDGE 800000
#define NB1   196        // ceil(50000/256)

// ---------------- CSR build: count, scan, fill ----------------

__global__ void k_count(const int* __restrict__ dst, int* __restrict__ cnt) {
    int i = blockIdx.x * 256 + threadIdx.x;
    if (i < NEDGE) atomicAdd(&cnt[dst[i]], 1);
}

__global__ void k_scan1(const int* __restrict__ cnt, int* __restrict__ incl, int* __restrict__ bsum) {
    __shared__ int s[256];
    int i = blockIdx.x * 256 + threadIdx.x;
    int v = (i < NNODE) ? cnt[i] : 0;
    s[threadIdx.x] = v;
    __syncthreads();
#pragma unroll
    for (int off = 1; off < 256; off <<= 1) {
        int t = (threadIdx.x >= off) ? s[threadIdx.x - off] : 0;
        __syncthreads();
        s[threadIdx.x] += t;
        __syncthreads();
    }
    if (i < NNODE) incl[i] = s[threadIdx.x];
    if (threadIdx.x == 255) bsum[blockIdx.x] = s[255];
}

__global__ void k_scan2(int* __restrict__ bsum) {
    __shared__ int s[256];
    int v = (threadIdx.x < NB1) ? bsum[threadIdx.x] : 0;
    s[threadIdx.x] = v;
    __syncthreads();
#pragma unroll
    for (int off = 1; off < 256; off <<= 1) {
        int t = (threadIdx.x >= off) ? s[threadIdx.x - off] : 0;
        __syncthreads();
        s[threadIdx.x] += t;
        __syncthreads();
    }
    if (threadIdx.x < NB1) bsum[threadIdx.x] = s[threadIdx.x];
}

__global__ void k_scan3(const int* __restrict__ incl, const int* __restrict__ bsum,
                        const int* __restrict__ cnt, int* __restrict__ rowstart,
                        int* __restrict__ cursor, float* __restrict__ dinv) {
    int i = blockIdx.x * 256 + threadIdx.x;
    if (i >= NNODE) return;
    int boff = (blockIdx.x == 0) ? 0 : bsum[blockIdx.x - 1];
    int inc = incl[i] + boff;
    rowstart[i + 1] = inc;
    cursor[i] = inc - cnt[i];
    dinv[i] = rsqrtf((float)cnt[i] + 1.0f);   // +1 self loop
    if (i == 0) rowstart[0] = 0;
}

__global__ void k_fill(const int* __restrict__ src, const int* __restrict__ dst,
                       int* __restrict__ cursor, int* __restrict__ csr_src) {
    int e = blockIdx.x * 256 + threadIdx.x;
    if (e >= NEDGE) return;
    int d = dst[e];
    int pos = atomicAdd(&cursor[d], 1);
    csr_src[pos] = src[e];
}

// ---------------- GEMM + prescale: 64x64 LDS tile ----------------
// Block = 64 rows x 64 cols. X staged TRANSPOSED Xt[k][row] (row-dim padded
// to 68), W staged Ws[k][col] (zero-padded to 64 cols). 256 threads = 16 row
// groups x 16 col groups, 4x4 outputs each. Per k: 2 ds_read_b128, both
// broadcast (4 / 16 distinct lines per wave) -> conflict-free; 16 FMAs into
// 16 independent accumulators. No global loads in the k-loop.

template<int FIN, int FOUT>
__launch_bounds__(256)
__global__ void k_gemm_prescale(const float* __restrict__ X, const float* __restrict__ W,
                                const float* __restrict__ dinv, float* __restrict__ XWs) {
    __shared__ float Xt[FIN * 68];
    __shared__ float Ws[FIN * 64];

    const int tid = threadIdx.x;
    const int r0 = blockIdx.x * 64;

    // stage W (coalesced; zero-pad cols >= FOUT)
    for (int idx = tid; idx < FIN * 64; idx += 256) {
        int k = idx >> 6, c = idx & 63;
        Ws[idx] = (c < FOUT) ? W[k * FOUT + c] : 0.0f;
    }

    // stage X transposed. lane mapping: r_lo = idx&7, chunk c = (idx>>3)&(CH-1)
    // -> wave reads 8 rows x 128B contiguous segments (good coalescing);
    // writes hit 16 banks (4-way, 1.58x) only during staging.
    constexpr int CH = FIN / 4;
    constexpr int CSH = (FIN == 128) ? 5 : 4;
    for (int idx = tid; idx < 64 * CH; idx += 256) {
        int r_lo = idx & 7;
        int c = (idx >> 3) & (CH - 1);
        int r = ((idx >> (3 + CSH)) << 3) + r_lo;
        int rr = r0 + r; if (rr >= NNODE) rr = NNODE - 1;   // clamp tail block
        float4 v = *(const float4*)(X + (size_t)rr * FIN + c * 4);
        Xt[(4 * c + 0) * 68 + r] = v.x;
        Xt[(4 * c + 1) * 68 + r] = v.y;
        Xt[(4 * c + 2) * 68 + r] = v.z;
        Xt[(4 * c + 3) * 68 + r] = v.w;
    }
    __syncthreads();

    const int cg = tid & 15;    // col group
    const int rg = tid >> 4;    // row group

    float acc[4][4] = {};
#pragma unroll 4
    for (int k = 0; k < FIN; ++k) {
        float4 xv = *(const float4*)&Xt[k * 68 + 4 * rg];
        float4 wv = *(const float4*)&Ws[k * 64 + 4 * cg];
#pragma unroll
        for (int i = 0; i < 4; ++i) {
            float xi = (i == 0) ? xv.x : (i == 1) ? xv.y : (i == 2) ? xv.z : xv.w;
            acc[i][0] = fmaf(xi, wv.x, acc[i][0]);
            acc[i][1] = fmaf(xi, wv.y, acc[i][1]);
            acc[i][2] = fmaf(xi, wv.z, acc[i][2]);
            acc[i][3] = fmaf(xi, wv.w, acc[i][3]);
        }
    }

    if (4 * cg + 4 <= FOUT) {
#pragma unroll
        for (int i = 0; i < 4; ++i) {
            int row = r0 + 4 * rg + i;
            if (row < NNODE) {
                float dv = dinv[row];
                float4 o = { acc[i][0] * dv, acc[i][1] * dv, acc[i][2] * dv, acc[i][3] * dv };
                *(float4*)(XWs + (size_t)row * FOUT + 4 * cg) = o;
            }
        }
    }
}

// ---------------- CSR aggregate + finalize ----------------
// out[d][f] = act(dinv[d] * (XWs[d][f] + sum_{e in row d} XWs[src_e][f]) + b[f])
// one wave per destination node; lane = feature; gather unrolled x8 for MLP.

template<int F, bool RELU>
__launch_bounds__(256)
__global__ void k_aggregate(const float* __restrict__ XWs, const int* __restrict__ rowstart,
                            const int* __restrict__ csr_src, const float* __restrict__ dinv,
                            const float* __restrict__ b, float* __restrict__ out) {
    int wid  = threadIdx.x >> 6;
    int lane = threadIdx.x & 63;
    int d = blockIdx.x * 4 + wid;
    if (d >= NNODE) return;

    int beg = rowstart[d];
    int end = rowstart[d + 1];

    float acc = (lane < F) ? XWs[(size_t)d * F + lane] : 0.0f;  // self loop

    for (int base = beg; base < end; base += 64) {
        int idx = base + lane;
        int sv = (idx < end) ? csr_src[idx] : 0;   // coalesced edge-list load
        int nv = min(64, end - base);
        int j = 0;
        for (; j + 8 <= nv; j += 8) {
            int s0 = __shfl(sv, j + 0), s1 = __shfl(sv, j + 1);
            int s2 = __shfl(sv, j + 2), s3 = __shfl(sv, j + 3);
            int s4 = __shfl(sv, j + 4), s5 = __shfl(sv, j + 5);
            int s6 = __shfl(sv, j + 6), s7 = __shfl(sv, j + 7);
            float v0 = XWs[(size_t)s0 * F + lane];
            float v1 = XWs[(size_t)s1 * F + lane];
            float v2 = XWs[(size_t)s2 * F + lane];
            float v3 = XWs[(size_t)s3 * F + lane];
            float v4 = XWs[(size_t)s4 * F + lane];
            float v5 = XWs[(size_t)s5 * F + lane];
            float v6 = XWs[(size_t)s6 * F + lane];
            float v7 = XWs[(size_t)s7 * F + lane];
            acc += v0; acc += v1; acc += v2; acc += v3;
            acc += v4; acc += v5; acc += v6; acc += v7;
        }
        for (; j + 4 <= nv; j += 4) {
            int s0 = __shfl(sv, j + 0), s1 = __shfl(sv, j + 1);
            int s2 = __shfl(sv, j + 2), s3 = __shfl(sv, j + 3);
            float v0 = XWs[(size_t)s0 * F + lane];
            float v1 = XWs[(size_t)s1 * F + lane];
            float v2 = XWs[(size_t)s2 * F + lane];
            float v3 = XWs[(size_t)s3 * F + lane];
            acc += v0; acc += v1; acc += v2; acc += v3;
        }
        for (; j < nv; ++j) {
            int s = __shfl(sv, j);
            acc += XWs[(size_t)s * F + lane];
        }
    }

    if (lane < F) {
        float v = fmaf(acc, dinv[d], b[lane]);
        out[(size_t)d * F + lane] = RELU ? fmaxf(v, 0.0f) : v;
    }
}

extern "C" void kernel_launch(void* const* d_in, const int* in_sizes, int n_in,
                              void* d_out, int out_size, void* d_ws, size_t ws_size,
                              hipStream_t stream) {
    const float* x  = (const float*)d_in[0];
    const int*   ei = (const int*)d_in[1];
    const float* W1 = (const float*)d_in[2];
    const float* b1 = (const float*)d_in[3];
    const float* W2 = (const float*)d_in[4];
    const float* b2 = (const float*)d_in[5];
    const float* W3 = (const float*)d_in[6];
    const float* b3 = (const float*)d_in[7];
    float* out = (float*)d_out;

    const int* src = ei;
    const int* dst = ei + NEDGE;

    char* p = (char*)d_ws;
    auto alloc = [&](size_t bytes) { char* r = p; p += (bytes + 255) & ~size_t(255); return r; };
    int*   cnt      = (int*)  alloc(NNODE * 4);
    int*   incl     = (int*)  alloc(NNODE * 4);
    int*   bsum     = (int*)  alloc(256 * 4);
    int*   rowstart = (int*)  alloc((NNODE + 1) * 4);
    int*   cursor   = (int*)  alloc(NNODE * 4);
    int*   csr_src  = (int*)  alloc(NEDGE * 4);
    float* dinv     = (float*)alloc(NNODE * 4);
    float* XWs      = (float*)alloc((size_t)NNODE * 64 * 4 + 256);
    float* H1       = (float*)alloc((size_t)NNODE * 64 * 4);
    float* H2       = (float*)alloc((size_t)NNODE * 64 * 4);

    const int B = 256;
    const int gN    = NB1;                        // 196
    const int gE    = (NEDGE + B - 1) / B;        // 3125
    const int gGemm = (NNODE + 63) / 64;          // 782 (64 rows/block)
    const int gAgg  = (NNODE + 3) / 4;            // 12500

    // CSR build + norm
    hipMemsetAsync(cnt, 0, NNODE * 4, stream);
    k_count<<<gE, B, 0, stream>>>(dst, cnt);
    k_scan1<<<gN, B, 0, stream>>>(cnt, incl, bsum);
    k_scan2<<<1,  B, 0, stream>>>(bsum);
    k_scan3<<<gN, B, 0, stream>>>(incl, bsum, cnt, rowstart, cursor, dinv);
    k_fill <<<gE, B, 0, stream>>>(src, dst, cursor, csr_src);

    // layer 1: 128 -> 64, relu
    k_gemm_prescale<128, 64><<<gGemm, B, 0, stream>>>(x, W1, dinv, XWs);
    k_aggregate<64, true><<<gAgg, B, 0, stream>>>(XWs, rowstart, csr_src, dinv, b1, H1);

    // layer 2: 64 -> 64, relu
    k_gemm_prescale<64, 64><<<gGemm, B, 0, stream>>>(H1, W2, dinv, XWs);
    k_aggregate<64, true><<<gAgg, B, 0, stream>>>(XWs, rowstart, csr_src, dinv, b2, H2);

    // layer 3: 64 -> 40, no act
    k_gemm_prescale<64, 40><<<gGemm, B, 0, stream>>>(H2, W3, dinv, XWs);
    k_aggregate<40, false><<<gAgg, B, 0, stream>>>(XWs, rowstart, csr_src, dinv, b3, out);
}

// Round 8
// 251.515 us; speedup vs baseline: 1.7015x; 1.0072x over previous
//
#include <hip/hip_runtime.h>

#define NNODE 50000
#define NEDGE 800000
#define NB1   196        // ceil(50000/256)

// ---------------- CSR build: count, scan, fill ----------------
// 4 edges/thread via int4: coalesced reads + 4 independent atomics in flight.

__global__ void k_count(const int* __restrict__ dst, int* __restrict__ cnt) {
    int t = blockIdx.x * 256 + threadIdx.x;
    int e0 = t * 4;
    if (e0 + 3 < NEDGE) {
        int4 d4 = *(const int4*)&dst[e0];
        atomicAdd(&cnt[d4.x], 1);
        atomicAdd(&cnt[d4.y], 1);
        atomicAdd(&cnt[d4.z], 1);
        atomicAdd(&cnt[d4.w], 1);
    } else {
        for (int e = e0; e < NEDGE; ++e) atomicAdd(&cnt[dst[e]], 1);
    }
}

__global__ void k_scan1(const int* __restrict__ cnt, int* __restrict__ incl, int* __restrict__ bsum) {
    __shared__ int s[256];
    int i = blockIdx.x * 256 + threadIdx.x;
    int v = (i < NNODE) ? cnt[i] : 0;
    s[threadIdx.x] = v;
    __syncthreads();
#pragma unroll
    for (int off = 1; off < 256; off <<= 1) {
        int t = (threadIdx.x >= off) ? s[threadIdx.x - off] : 0;
        __syncthreads();
        s[threadIdx.x] += t;
        __syncthreads();
    }
    if (i < NNODE) incl[i] = s[threadIdx.x];
    if (threadIdx.x == 255) bsum[blockIdx.x] = s[255];
}

__global__ void k_scan2(int* __restrict__ bsum) {
    __shared__ int s[256];
    int v = (threadIdx.x < NB1) ? bsum[threadIdx.x] : 0;
    s[threadIdx.x] = v;
    __syncthreads();
#pragma unroll
    for (int off = 1; off < 256; off <<= 1) {
        int t = (threadIdx.x >= off) ? s[threadIdx.x - off] : 0;
        __syncthreads();
        s[threadIdx.x] += t;
        __syncthreads();
    }
    if (threadIdx.x < NB1) bsum[threadIdx.x] = s[threadIdx.x];
}

__global__ void k_scan3(const int* __restrict__ incl, const int* __restrict__ bsum,
                        const int* __restrict__ cnt, int* __restrict__ rowstart,
                        int* __restrict__ cursor, float* __restrict__ dinv) {
    int i = blockIdx.x * 256 + threadIdx.x;
    if (i >= NNODE) return;
    int boff = (blockIdx.x == 0) ? 0 : bsum[blockIdx.x - 1];
    int inc = incl[i] + boff;
    rowstart[i + 1] = inc;
    cursor[i] = inc - cnt[i];
    dinv[i] = rsqrtf((float)cnt[i] + 1.0f);   // +1 self loop
    if (i == 0) rowstart[0] = 0;
}

__global__ void k_fill(const int* __restrict__ src, const int* __restrict__ dst,
                       int* __restrict__ cursor, int* __restrict__ csr_src) {
    int t = blockIdx.x * 256 + threadIdx.x;
    int e0 = t * 4;
    if (e0 + 3 < NEDGE) {
        int4 d4 = *(const int4*)&dst[e0];
        int4 s4 = *(const int4*)&src[e0];
        int p0 = atomicAdd(&cursor[d4.x], 1);   // 4 independent round trips in flight
        int p1 = atomicAdd(&cursor[d4.y], 1);
        int p2 = atomicAdd(&cursor[d4.z], 1);
        int p3 = atomicAdd(&cursor[d4.w], 1);
        csr_src[p0] = s4.x;
        csr_src[p1] = s4.y;
        csr_src[p2] = s4.z;
        csr_src[p3] = s4.w;
    } else {
        for (int e = e0; e < NEDGE; ++e) {
            int pos = atomicAdd(&cursor[dst[e]], 1);
            csr_src[pos] = src[e];
        }
    }
}

// ---------------- GEMM + prescale: 64x64 LDS tile ----------------
// Block = 64 rows x 64 cols. X staged TRANSPOSED Xt[k][row] (row-dim padded
// to 68), W staged Ws[k][col] (zero-padded to 64 cols). 256 threads = 16 row
// groups x 16 col groups, 4x4 outputs each. Per k: 2 ds_read_b128, both
// broadcast -> conflict-free; 16 FMAs into 16 independent accumulators.

template<int FIN, int FOUT>
__launch_bounds__(256)
__global__ void k_gemm_prescale(const float* __restrict__ X, const float* __restrict__ W,
                                const float* __restrict__ dinv, float* __restrict__ XWs) {
    __shared__ float Xt[FIN * 68];
    __shared__ float Ws[FIN * 64];

    const int tid = threadIdx.x;
    const int r0 = blockIdx.x * 64;

    for (int idx = tid; idx < FIN * 64; idx += 256) {
        int k = idx >> 6, c = idx & 63;
        Ws[idx] = (c < FOUT) ? W[k * FOUT + c] : 0.0f;
    }

    constexpr int CH = FIN / 4;
    constexpr int CSH = (FIN == 128) ? 5 : 4;
    for (int idx = tid; idx < 64 * CH; idx += 256) {
        int r_lo = idx & 7;
        int c = (idx >> 3) & (CH - 1);
        int r = ((idx >> (3 + CSH)) << 3) + r_lo;
        int rr = r0 + r; if (rr >= NNODE) rr = NNODE - 1;   // clamp tail block
        float4 v = *(const float4*)(X + (size_t)rr * FIN + c * 4);
        Xt[(4 * c + 0) * 68 + r] = v.x;
        Xt[(4 * c + 1) * 68 + r] = v.y;
        Xt[(4 * c + 2) * 68 + r] = v.z;
        Xt[(4 * c + 3) * 68 + r] = v.w;
    }
    __syncthreads();

    const int cg = tid & 15;    // col group
    const int rg = tid >> 4;    // row group

    float acc[4][4] = {};
#pragma unroll 4
    for (int k = 0; k < FIN; ++k) {
        float4 xv = *(const float4*)&Xt[k * 68 + 4 * rg];
        float4 wv = *(const float4*)&Ws[k * 64 + 4 * cg];
#pragma unroll
        for (int i = 0; i < 4; ++i) {
            float xi = (i == 0) ? xv.x : (i == 1) ? xv.y : (i == 2) ? xv.z : xv.w;
            acc[i][0] = fmaf(xi, wv.x, acc[i][0]);
            acc[i][1] = fmaf(xi, wv.y, acc[i][1]);
            acc[i][2] = fmaf(xi, wv.z, acc[i][2]);
            acc[i][3] = fmaf(xi, wv.w, acc[i][3]);
        }
    }

    if (4 * cg + 4 <= FOUT) {
#pragma unroll
        for (int i = 0; i < 4; ++i) {
            int row = r0 + 4 * rg + i;
            if (row < NNODE) {
                float dv = dinv[row];
                float4 o = { acc[i][0] * dv, acc[i][1] * dv, acc[i][2] * dv, acc[i][3] * dv };
                *(float4*)(XWs + (size_t)row * FOUT + 4 * cg) = o;
            }
        }
    }
}

// ---------------- CSR aggregate + finalize ----------------
// one wave per destination node; lane = feature; gather unrolled x8 for MLP.

template<int F, bool RELU>
__launch_bounds__(256)
__global__ void k_aggregate(const float* __restrict__ XWs, const int* __restrict__ rowstart,
                            const int* __restrict__ csr_src, const float* __restrict__ dinv,
                            const float* __restrict__ b, float* __restrict__ out) {
    int wid  = threadIdx.x >> 6;
    int lane = threadIdx.x & 63;
    int d = blockIdx.x * 4 + wid;
    if (d >= NNODE) return;

    int beg = rowstart[d];
    int end = rowstart[d + 1];

    float acc = (lane < F) ? XWs[(size_t)d * F + lane] : 0.0f;  // self loop

    for (int base = beg; base < end; base += 64) {
        int idx = base + lane;
        int sv = (idx < end) ? csr_src[idx] : 0;   // coalesced edge-list load
        int nv = min(64, end - base);
        int j = 0;
        for (; j + 8 <= nv; j += 8) {
            int s0 = __shfl(sv, j + 0), s1 = __shfl(sv, j + 1);
            int s2 = __shfl(sv, j + 2), s3 = __shfl(sv, j + 3);
            int s4 = __shfl(sv, j + 4), s5 = __shfl(sv, j + 5);
            int s6 = __shfl(sv, j + 6), s7 = __shfl(sv, j + 7);
            float v0 = XWs[(size_t)s0 * F + lane];
            float v1 = XWs[(size_t)s1 * F + lane];
            float v2 = XWs[(size_t)s2 * F + lane];
            float v3 = XWs[(size_t)s3 * F + lane];
            float v4 = XWs[(size_t)s4 * F + lane];
            float v5 = XWs[(size_t)s5 * F + lane];
            float v6 = XWs[(size_t)s6 * F + lane];
            float v7 = XWs[(size_t)s7 * F + lane];
            acc += v0; acc += v1; acc += v2; acc += v3;
            acc += v4; acc += v5; acc += v6; acc += v7;
        }
        for (; j + 4 <= nv; j += 4) {
            int s0 = __shfl(sv, j + 0), s1 = __shfl(sv, j + 1);
            int s2 = __shfl(sv, j + 2), s3 = __shfl(sv, j + 3);
            float v0 = XWs[(size_t)s0 * F + lane];
            float v1 = XWs[(size_t)s1 * F + lane];
            float v2 = XWs[(size_t)s2 * F + lane];
            float v3 = XWs[(size_t)s3 * F + lane];
            acc += v0; acc += v1; acc += v2; acc += v3;
        }
        for (; j < nv; ++j) {
            int s = __shfl(sv, j);
            acc += XWs[(size_t)s * F + lane];
        }
    }

    if (lane < F) {
        float v = fmaf(acc, dinv[d], b[lane]);
        out[(size_t)d * F + lane] = RELU ? fmaxf(v, 0.0f) : v;
    }
}

extern "C" void kernel_launch(void* const* d_in, const int* in_sizes, int n_in,
                              void* d_out, int out_size, void* d_ws, size_t ws_size,
                              hipStream_t stream) {
    const float* x  = (const float*)d_in[0];
    const int*   ei = (const int*)d_in[1];
    const float* W1 = (const float*)d_in[2];
    const float* b1 = (const float*)d_in[3];
    const float* W2 = (const float*)d_in[4];
    const float* b2 = (const float*)d_in[5];
    const float* W3 = (const float*)d_in[6];
    const float* b3 = (const float*)d_in[7];
    float* out = (float*)d_out;

    const int* src = ei;
    const int* dst = ei + NEDGE;

    char* p = (char*)d_ws;
    auto alloc = [&](size_t bytes) { char* r = p; p += (bytes + 255) & ~size_t(255); return r; };
    int*   cnt      = (int*)  alloc(NNODE * 4);
    int*   incl     = (int*)  alloc(NNODE * 4);
    int*   bsum     = (int*)  alloc(256 * 4);
    int*   rowstart = (int*)  alloc((NNODE + 1) * 4);
    int*   cursor   = (int*)  alloc(NNODE * 4);
    int*   csr_src  = (int*)  alloc(NEDGE * 4);
    float* dinv     = (float*)alloc(NNODE * 4);
    float* XWs      = (float*)alloc((size_t)NNODE * 64 * 4 + 256);
    float* H1       = (float*)alloc((size_t)NNODE * 64 * 4);
    float* H2       = (float*)alloc((size_t)NNODE * 64 * 4);

    const int B = 256;
    const int gN    = NB1;                        // 196
    const int gE4   = (NEDGE / 4 + B - 1) / B;    // 782 (4 edges/thread)
    const int gGemm = (NNODE + 63) / 64;          // 782 (64 rows/block)
    const int gAgg  = (NNODE + 3) / 4;            // 12500

    // CSR build + norm
    hipMemsetAsync(cnt, 0, NNODE * 4, stream);
    k_count<<<gE4, B, 0, stream>>>(dst, cnt);
    k_scan1<<<gN, B, 0, stream>>>(cnt, incl, bsum);
    k_scan2<<<1,  B, 0, stream>>>(bsum);
    k_scan3<<<gN, B, 0, stream>>>(incl, bsum, cnt, rowstart, cursor, dinv);
    k_fill <<<gE4, B, 0, stream>>>(src, dst, cursor, csr_src);

    // layer 1: 128 -> 64, relu
    k_gemm_prescale<128, 64><<<gGemm, B, 0, stream>>>(x, W1, dinv, XWs);
    k_aggregate<64, true><<<gAgg, B, 0, stream>>>(XWs, rowstart, csr_src, dinv, b1, H1);

    // layer 2: 64 -> 64, relu
    k_gemm_prescale<64, 64><<<gGemm, B, 0, stream>>>(H1, W2, dinv, XWs);
    k_aggregate<64, true><<<gAgg, B, 0, stream>>>(XWs, rowstart, csr_src, dinv, b2, H2);

    // layer 3: 64 -> 40, no act
    k_gemm_prescale<64, 40><<<gGemm, B, 0, stream>>>(H2, W3, dinv, XWs);
    k_aggregate<40, false><<<gAgg, B, 0, stream>>>(XWs, rowstart, csr_src, dinv, b3, out);
}

// Round 9
// 250.112 us; speedup vs baseline: 1.7111x; 1.0056x over previous
//
#include <hip/hip_runtime.h>

#define NNODE 50000
#define NEDGE 800000
#define NBUCKET 98          // ceil(50000 / 512)
#define EPB 3125            // NEDGE / 256 edges per producer block

// ---------------- Pass A: bucketize edges by dst>>9 ----------------
// 256 blocks, each owns edges [pb*3125, (pb+1)*3125): LDS histogram over 98
// buckets, LDS scan, then scatter packed (dst<<16|src) into the block's OWN
// contiguous region of `bucketed`, grouped by bucket. All writes land in a
// 12.5 KB block-local range -> full-line HBM writes (no 16x amplification).

__global__ __launch_bounds__(256) void k_bucketA(const int* __restrict__ src, const int* __restrict__ dst,
                         int* __restrict__ hist_g, int* __restrict__ runstart_g,
                         unsigned int* __restrict__ bucketed, int* __restrict__ bucketsize) {
    __shared__ int h[NBUCKET];
    __shared__ int start[NBUCKET];   // becomes cursor
    const int tid = threadIdx.x;
    const int pb = blockIdx.x;
    const int e0 = pb * EPB;

    for (int i = tid; i < NBUCKET; i += 256) h[i] = 0;
    __syncthreads();

    for (int i = tid; i < EPB; i += 256)
        atomicAdd(&h[dst[e0 + i] >> 9], 1);
    __syncthreads();

    if (tid == 0) {
        int run = 0;
        for (int b = 0; b < NBUCKET; ++b) { start[b] = run; run += h[b]; }
    }
    __syncthreads();

    if (tid < NBUCKET) {
        hist_g[pb * NBUCKET + tid] = h[tid];
        runstart_g[pb * NBUCKET + tid] = e0 + start[tid];
        atomicAdd(&bucketsize[tid], h[tid]);
        start[tid] += e0;            // global cursor
    }
    __syncthreads();

    for (int i = tid; i < EPB; i += 256) {
        int d = dst[e0 + i];
        int s = src[e0 + i];
        int b = d >> 9;
        int pos = atomicAdd(&start[b], 1);
        bucketed[pos] = ((unsigned int)d << 16) | (unsigned int)s;
    }
}

// ---------------- bucket base: exclusive scan of 98 sizes ----------------

__global__ void k_bucketbase(const int* __restrict__ bucketsize, int* __restrict__ bucketbase,
                             int* __restrict__ rowstart) {
    __shared__ int ls[NBUCKET];
    int t = threadIdx.x;
    if (t < NBUCKET) ls[t] = bucketsize[t];
    __syncthreads();
    if (t == 0) {
        int run = 0;
        for (int b = 0; b < NBUCKET; ++b) { bucketbase[b] = run; run += ls[b]; }
        bucketbase[NBUCKET] = run;       // == NEDGE
        rowstart[NNODE] = NEDGE;
    }
}

// ---------------- Pass B: per-bucket CSR + dinv ----------------
// 98 blocks; block b owns nodes [b*512, b*512+512). Histogram its ~8k edges
// into 512 LDS counters (wave w walks producer runs pb = w,w+4,...), parallel
// scan, write rowstart/dinv, then scatter csr_src into the bucket's
// contiguous output range.

__global__ __launch_bounds__(256) void k_bucketB(const unsigned int* __restrict__ bucketed,
                         const int* __restrict__ hist_g, const int* __restrict__ runstart_g,
                         const int* __restrict__ bucketbase, int* __restrict__ rowstart,
                         int* __restrict__ csr_src, float* __restrict__ dinv) {
    __shared__ int cnt[512];
    __shared__ int ex[512];
    __shared__ int cur[512];
    const int tid = threadIdx.x;
    const int wid = tid >> 6, lane = tid & 63;
    const int b = blockIdx.x;
    const int base_node = b << 9;
    const int base_out = bucketbase[b];

    cnt[tid] = 0; cnt[tid + 256] = 0;
    __syncthreads();

    for (int pb = wid; pb < 256; pb += 4) {
        int s = runstart_g[pb * NBUCKET + b];
        int e = s + hist_g[pb * NBUCKET + b];
        for (int i = s + lane; i < e; i += 64) {
            int dl = (int)(bucketed[i] >> 16) - base_node;
            atomicAdd(&cnt[dl], 1);
        }
    }
    __syncthreads();

    // inclusive scan of cnt -> ex (Hillis-Steele, 2 elems/thread)
    ex[tid] = cnt[tid]; ex[tid + 256] = cnt[tid + 256];
    __syncthreads();
    for (int off = 1; off < 512; off <<= 1) {
        int i0 = tid, i1 = tid + 256;
        int a0 = (i0 >= off) ? ex[i0 - off] : 0;
        int a1 = (i1 >= off) ? ex[i1 - off] : 0;
        __syncthreads();
        ex[i0] += a0; ex[i1] += a1;
        __syncthreads();
    }

    // rowstart / dinv / cursors (excl = incl - cnt)
#pragma unroll
    for (int rep = 0; rep < 2; ++rep) {
        int i = tid + rep * 256;
        int node = base_node + i;
        int excl = ex[i] - cnt[i];
        cur[i] = base_out + excl;
        if (node < NNODE) {
            rowstart[node] = base_out + excl;
            dinv[node] = rsqrtf((float)cnt[i] + 1.0f);
        }
    }
    __syncthreads();

    for (int pb = wid; pb < 256; pb += 4) {
        int s = runstart_g[pb * NBUCKET + b];
        int e = s + hist_g[pb * NBUCKET + b];
        for (int i = s + lane; i < e; i += 64) {
            unsigned int u = bucketed[i];
            int dl = (int)(u >> 16) - base_node;
            int pos = atomicAdd(&cur[dl], 1);
            csr_src[pos] = (int)(u & 0xFFFFu);
        }
    }
}

// ---------------- GEMM + prescale: 64x64 LDS tile (unchanged R7) ----------------

template<int FIN, int FOUT>
__launch_bounds__(256)
__global__ void k_gemm_prescale(const float* __restrict__ X, const float* __restrict__ W,
                                const float* __restrict__ dinv, float* __restrict__ XWs) {
    __shared__ float Xt[FIN * 68];
    __shared__ float Ws[FIN * 64];

    const int tid = threadIdx.x;
    const int r0 = blockIdx.x * 64;

    for (int idx = tid; idx < FIN * 64; idx += 256) {
        int k = idx >> 6, c = idx & 63;
        Ws[idx] = (c < FOUT) ? W[k * FOUT + c] : 0.0f;
    }

    constexpr int CH = FIN / 4;
    constexpr int CSH = (FIN == 128) ? 5 : 4;
    for (int idx = tid; idx < 64 * CH; idx += 256) {
        int r_lo = idx & 7;
        int c = (idx >> 3) & (CH - 1);
        int r = ((idx >> (3 + CSH)) << 3) + r_lo;
        int rr = r0 + r; if (rr >= NNODE) rr = NNODE - 1;   // clamp tail block
        float4 v = *(const float4*)(X + (size_t)rr * FIN + c * 4);
        Xt[(4 * c + 0) * 68 + r] = v.x;
        Xt[(4 * c + 1) * 68 + r] = v.y;
        Xt[(4 * c + 2) * 68 + r] = v.z;
        Xt[(4 * c + 3) * 68 + r] = v.w;
    }
    __syncthreads();

    const int cg = tid & 15;    // col group
    const int rg = tid >> 4;    // row group

    float acc[4][4] = {};
#pragma unroll 4
    for (int k = 0; k < FIN; ++k) {
        float4 xv = *(const float4*)&Xt[k * 68 + 4 * rg];
        float4 wv = *(const float4*)&Ws[k * 64 + 4 * cg];
#pragma unroll
        for (int i = 0; i < 4; ++i) {
            float xi = (i == 0) ? xv.x : (i == 1) ? xv.y : (i == 2) ? xv.z : xv.w;
            acc[i][0] = fmaf(xi, wv.x, acc[i][0]);
            acc[i][1] = fmaf(xi, wv.y, acc[i][1]);
            acc[i][2] = fmaf(xi, wv.z, acc[i][2]);
            acc[i][3] = fmaf(xi, wv.w, acc[i][3]);
        }
    }

    if (4 * cg + 4 <= FOUT) {
#pragma unroll
        for (int i = 0; i < 4; ++i) {
            int row = r0 + 4 * rg + i;
            if (row < NNODE) {
                float dv = dinv[row];
                float4 o = { acc[i][0] * dv, acc[i][1] * dv, acc[i][2] * dv, acc[i][3] * dv };
                *(float4*)(XWs + (size_t)row * FOUT + 4 * cg) = o;
            }
        }
    }
}

// ---------------- CSR aggregate + finalize (unchanged R7) ----------------

template<int F, bool RELU>
__launch_bounds__(256)
__global__ void k_aggregate(const float* __restrict__ XWs, const int* __restrict__ rowstart,
                            const int* __restrict__ csr_src, const float* __restrict__ dinv,
                            const float* __restrict__ b, float* __restrict__ out) {
    int wid  = threadIdx.x >> 6;
    int lane = threadIdx.x & 63;
    int d = blockIdx.x * 4 + wid;
    if (d >= NNODE) return;

    int beg = rowstart[d];
    int end = rowstart[d + 1];

    float acc = (lane < F) ? XWs[(size_t)d * F + lane] : 0.0f;  // self loop

    for (int base = beg; base < end; base += 64) {
        int idx = base + lane;
        int sv = (idx < end) ? csr_src[idx] : 0;   // coalesced edge-list load
        int nv = min(64, end - base);
        int j = 0;
        for (; j + 8 <= nv; j += 8) {
            int s0 = __shfl(sv, j + 0), s1 = __shfl(sv, j + 1);
            int s2 = __shfl(sv, j + 2), s3 = __shfl(sv, j + 3);
            int s4 = __shfl(sv, j + 4), s5 = __shfl(sv, j + 5);
            int s6 = __shfl(sv, j + 6), s7 = __shfl(sv, j + 7);
            float v0 = XWs[(size_t)s0 * F + lane];
            float v1 = XWs[(size_t)s1 * F + lane];
            float v2 = XWs[(size_t)s2 * F + lane];
            float v3 = XWs[(size_t)s3 * F + lane];
            float v4 = XWs[(size_t)s4 * F + lane];
            float v5 = XWs[(size_t)s5 * F + lane];
            float v6 = XWs[(size_t)s6 * F + lane];
            float v7 = XWs[(size_t)s7 * F + lane];
            acc += v0; acc += v1; acc += v2; acc += v3;
            acc += v4; acc += v5; acc += v6; acc += v7;
        }
        for (; j + 4 <= nv; j += 4) {
            int s0 = __shfl(sv, j + 0), s1 = __shfl(sv, j + 1);
            int s2 = __shfl(sv, j + 2), s3 = __shfl(sv, j + 3);
            float v0 = XWs[(size_t)s0 * F + lane];
            float v1 = XWs[(size_t)s1 * F + lane];
            float v2 = XWs[(size_t)s2 * F + lane];
            float v3 = XWs[(size_t)s3 * F + lane];
            acc += v0; acc += v1; acc += v2; acc += v3;
        }
        for (; j < nv; ++j) {
            int s = __shfl(sv, j);
            acc += XWs[(size_t)s * F + lane];
        }
    }

    if (lane < F) {
        float v = fmaf(acc, dinv[d], b[lane]);
        out[(size_t)d * F + lane] = RELU ? fmaxf(v, 0.0f) : v;
    }
}

extern "C" void kernel_launch(void* const* d_in, const int* in_sizes, int n_in,
                              void* d_out, int out_size, void* d_ws, size_t ws_size,
                              hipStream_t stream) {
    const float* x  = (const float*)d_in[0];
    const int*   ei = (const int*)d_in[1];
    const float* W1 = (const float*)d_in[2];
    const float* b1 = (const float*)d_in[3];
    const float* W2 = (const float*)d_in[4];
    const float* b2 = (const float*)d_in[5];
    const float* W3 = (const float*)d_in[6];
    const float* b3 = (const float*)d_in[7];
    float* out = (float*)d_out;

    const int* src = ei;
    const int* dst = ei + NEDGE;

    char* p = (char*)d_ws;
    auto alloc = [&](size_t bytes) { char* r = p; p += (bytes + 255) & ~size_t(255); return r; };
    unsigned int* bucketed = (unsigned int*)alloc((size_t)NEDGE * 4);
    int*   hist_g     = (int*)  alloc(256 * NBUCKET * 4);
    int*   runstart_g = (int*)  alloc(256 * NBUCKET * 4);
    int*   bucketsize = (int*)  alloc((NBUCKET + 1) * 4);
    int*   bucketbase = (int*)  alloc((NBUCKET + 1) * 4);
    int*   rowstart   = (int*)  alloc((NNODE + 1) * 4);
    int*   csr_src    = (int*)  alloc((size_t)NEDGE * 4);
    float* dinv       = (float*)alloc(NNODE * 4);
    float* XWs        = (float*)alloc((size_t)NNODE * 64 * 4 + 256);
    float* H1         = (float*)alloc((size_t)NNODE * 64 * 4);
    float* H2         = (float*)alloc((size_t)NNODE * 64 * 4);

    const int B = 256;
    const int gGemm = (NNODE + 63) / 64;          // 782 (64 rows/block)
    const int gAgg  = (NNODE + 3) / 4;            // 12500

    // CSR build + norm (bucketed counting sort)
    hipMemsetAsync(bucketsize, 0, (NBUCKET + 1) * 4, stream);
    k_bucketA<<<256, B, 0, stream>>>(src, dst, hist_g, runstart_g, bucketed, bucketsize);
    k_bucketbase<<<1, 128, 0, stream>>>(bucketsize, bucketbase, rowstart);
    k_bucketB<<<NBUCKET, B, 0, stream>>>(bucketed, hist_g, runstart_g, bucketbase,
                                         rowstart, csr_src, dinv);

    // layer 1: 128 -> 64, relu
    k_gemm_prescale<128, 64><<<gGemm, B, 0, stream>>>(x, W1, dinv, XWs);
    k_aggregate<64, true><<<gAgg, B, 0, stream>>>(XWs, rowstart, csr_src, dinv, b1, H1);

    // layer 2: 64 -> 64, relu
    k_gemm_prescale<64, 64><<<gGemm, B, 0, stream>>>(H1, W2, dinv, XWs);
    k_aggregate<64, true><<<gAgg, B, 0, stream>>>(XWs, rowstart, csr_src, dinv, b2, H2);

    // layer 3: 64 -> 40, no act
    k_gemm_prescale<64, 40><<<gGemm, B, 0, stream>>>(H2, W3, dinv, XWs);
    k_aggregate<40, false><<<gAgg, B, 0, stream>>>(XWs, rowstart, csr_src, dinv, b3, out);
}

// Round 10
// 178.220 us; speedup vs baseline: 2.4013x; 1.4034x over previous
//
#include <hip/hip_runtime.h>

#define NNODE 50000
#define NEDGE 800000
#define NBUCKET 196         // ceil(50000 / 256), bucket = dst >> 8
#define NPB 256             // nodes per bucket
#define EPB 3125            // NEDGE / 256 edges per producer block

// ---------------- Pass A: deterministic-base bucketize (bucket = dst>>8) ----

// per-producer-block histogram, stored TRANSPOSED: hist_g[b*256 + pb]
__global__ __launch_bounds__(256) void k_histA(const int* __restrict__ dst, int* __restrict__ hist_g) {
    __shared__ int h[NBUCKET];
    const int tid = threadIdx.x, pb = blockIdx.x, e0 = pb * EPB;
    if (tid < NBUCKET) h[tid] = 0;
    __syncthreads();
    for (int i = tid; i < EPB; i += 256)
        atomicAdd(&h[dst[e0 + i] >> 8], 1);
    __syncthreads();
    if (tid < NBUCKET) hist_g[tid * 256 + pb] = h[tid];
}

// per-bucket exclusive scan over producers; colsum[b] = bucket size
__global__ __launch_bounds__(256) void k_scanA1(const int* __restrict__ hist_g, int* __restrict__ base_g,
                                                int* __restrict__ colsum) {
    __shared__ int s[256];
    const int b = blockIdx.x, t = threadIdx.x;
    int v = hist_g[b * 256 + t];
    s[t] = v;
    __syncthreads();
#pragma unroll
    for (int off = 1; off < 256; off <<= 1) {
        int a = (t >= off) ? s[t - off] : 0;
        __syncthreads();
        s[t] += a;
        __syncthreads();
    }
    base_g[b * 256 + t] = s[t] - v;           // exclusive
    if (t == 255) colsum[b] = s[t];
}

// scan bucket sizes -> bucketbase
__global__ __launch_bounds__(256) void k_scanA2(const int* __restrict__ colsum, int* __restrict__ bucketbase,
                                                int* __restrict__ rowstart) {
    __shared__ int s[256];
    const int t = threadIdx.x;
    int v = (t < NBUCKET) ? colsum[t] : 0;
    s[t] = v;
    __syncthreads();
#pragma unroll
    for (int off = 1; off < 256; off <<= 1) {
        int a = (t >= off) ? s[t - off] : 0;
        __syncthreads();
        s[t] += a;
        __syncthreads();
    }
    if (t < NBUCKET) bucketbase[t] = s[t] - v;
    if (t == 0) { bucketbase[NBUCKET] = NEDGE; rowstart[NNODE] = NEDGE; }
}

// scatter packed edges to deterministic per-block per-bucket bases
__global__ __launch_bounds__(256) void k_scatterA(const int* __restrict__ src, const int* __restrict__ dst,
                          const int* __restrict__ base_g, const int* __restrict__ bucketbase,
                          unsigned int* __restrict__ bucketed) {
    __shared__ int cur[NBUCKET];
    const int tid = threadIdx.x, pb = blockIdx.x, e0 = pb * EPB;
    if (tid < NBUCKET) cur[tid] = bucketbase[tid] + base_g[tid * 256 + pb];
    __syncthreads();
    for (int i = tid; i < EPB; i += 256) {
        int d = dst[e0 + i], s = src[e0 + i];
        int pos = atomicAdd(&cur[d >> 8], 1);
        bucketed[pos] = ((unsigned int)d << 16) | (unsigned int)s;
    }
}

// ---------------- Pass B: per-bucket fine CSR (contiguous reads) ----------

__global__ __launch_bounds__(256) void k_bucketB2(const unsigned int* __restrict__ bucketed,
                          const int* __restrict__ bucketbase, int* __restrict__ rowstart,
                          int* __restrict__ csr_src, float* __restrict__ dinv) {
    __shared__ int cnt[NPB];
    __shared__ int ex[NPB];
    __shared__ int cur[NPB];
    const int tid = threadIdx.x, b = blockIdx.x;
    const int base_out = bucketbase[b], end_out = bucketbase[b + 1];

    cnt[tid] = 0;
    __syncthreads();
    for (int i = base_out + tid; i < end_out; i += 256)
        atomicAdd(&cnt[(bucketed[i] >> 16) & 255], 1);
    __syncthreads();

    int v = cnt[tid];
    ex[tid] = v;
    __syncthreads();
#pragma unroll
    for (int off = 1; off < 256; off <<= 1) {
        int a = (tid >= off) ? ex[tid - off] : 0;
        __syncthreads();
        ex[tid] += a;
        __syncthreads();
    }
    int excl = ex[tid] - v;
    int node = (b << 8) + tid;
    cur[tid] = base_out + excl;
    if (node < NNODE) {
        rowstart[node] = base_out + excl;
        dinv[node] = rsqrtf((float)v + 1.0f);
    }
    __syncthreads();

    for (int i = base_out + tid; i < end_out; i += 256) {
        unsigned int u = bucketed[i];
        int pos = atomicAdd(&cur[(u >> 16) & 255], 1);
        csr_src[pos] = (int)(u & 0xFFFFu);
    }
}

// ---------------- GEMM + prescale: 64x64 LDS tile (unchanged R7) ----------------

template<int FIN, int FOUT>
__launch_bounds__(256)
__global__ void k_gemm_prescale(const float* __restrict__ X, const float* __restrict__ W,
                                const float* __restrict__ dinv, float* __restrict__ XWs) {
    __shared__ float Xt[FIN * 68];
    __shared__ float Ws[FIN * 64];

    const int tid = threadIdx.x;
    const int r0 = blockIdx.x * 64;

    for (int idx = tid; idx < FIN * 64; idx += 256) {
        int k = idx >> 6, c = idx & 63;
        Ws[idx] = (c < FOUT) ? W[k * FOUT + c] : 0.0f;
    }

    constexpr int CH = FIN / 4;
    constexpr int CSH = (FIN == 128) ? 5 : 4;
    for (int idx = tid; idx < 64 * CH; idx += 256) {
        int r_lo = idx & 7;
        int c = (idx >> 3) & (CH - 1);
        int r = ((idx >> (3 + CSH)) << 3) + r_lo;
        int rr = r0 + r; if (rr >= NNODE) rr = NNODE - 1;   // clamp tail block
        float4 v = *(const float4*)(X + (size_t)rr * FIN + c * 4);
        Xt[(4 * c + 0) * 68 + r] = v.x;
        Xt[(4 * c + 1) * 68 + r] = v.y;
        Xt[(4 * c + 2) * 68 + r] = v.z;
        Xt[(4 * c + 3) * 68 + r] = v.w;
    }
    __syncthreads();

    const int cg = tid & 15;    // col group
    const int rg = tid >> 4;    // row group

    float acc[4][4] = {};
#pragma unroll 4
    for (int k = 0; k < FIN; ++k) {
        float4 xv = *(const float4*)&Xt[k * 68 + 4 * rg];
        float4 wv = *(const float4*)&Ws[k * 64 + 4 * cg];
#pragma unroll
        for (int i = 0; i < 4; ++i) {
            float xi = (i == 0) ? xv.x : (i == 1) ? xv.y : (i == 2) ? xv.z : xv.w;
            acc[i][0] = fmaf(xi, wv.x, acc[i][0]);
            acc[i][1] = fmaf(xi, wv.y, acc[i][1]);
            acc[i][2] = fmaf(xi, wv.z, acc[i][2]);
            acc[i][3] = fmaf(xi, wv.w, acc[i][3]);
        }
    }

    if (4 * cg + 4 <= FOUT) {
#pragma unroll
        for (int i = 0; i < 4; ++i) {
            int row = r0 + 4 * rg + i;
            if (row < NNODE) {
                float dv = dinv[row];
                float4 o = { acc[i][0] * dv, acc[i][1] * dv, acc[i][2] * dv, acc[i][3] * dv };
                *(float4*)(XWs + (size_t)row * FOUT + 4 * cg) = o;
            }
        }
    }
}

// ---------------- CSR aggregate + finalize (unchanged R7) ----------------

template<int F, bool RELU>
__launch_bounds__(256)
__global__ void k_aggregate(const float* __restrict__ XWs, const int* __restrict__ rowstart,
                            const int* __restrict__ csr_src, const float* __restrict__ dinv,
                            const float* __restrict__ b, float* __restrict__ out) {
    int wid  = threadIdx.x >> 6;
    int lane = threadIdx.x & 63;
    int d = blockIdx.x * 4 + wid;
    if (d >= NNODE) return;

    int beg = rowstart[d];
    int end = rowstart[d + 1];

    float acc = (lane < F) ? XWs[(size_t)d * F + lane] : 0.0f;  // self loop

    for (int base = beg; base < end; base += 64) {
        int idx = base + lane;
        int sv = (idx < end) ? csr_src[idx] : 0;   // coalesced edge-list load
        int nv = min(64, end - base);
        int j = 0;
        for (; j + 8 <= nv; j += 8) {
            int s0 = __shfl(sv, j + 0), s1 = __shfl(sv, j + 1);
            int s2 = __shfl(sv, j + 2), s3 = __shfl(sv, j + 3);
            int s4 = __shfl(sv, j + 4), s5 = __shfl(sv, j + 5);
            int s6 = __shfl(sv, j + 6), s7 = __shfl(sv, j + 7);
            float v0 = XWs[(size_t)s0 * F + lane];
            float v1 = XWs[(size_t)s1 * F + lane];
            float v2 = XWs[(size_t)s2 * F + lane];
            float v3 = XWs[(size_t)s3 * F + lane];
            float v4 = XWs[(size_t)s4 * F + lane];
            float v5 = XWs[(size_t)s5 * F + lane];
            float v6 = XWs[(size_t)s6 * F + lane];
            float v7 = XWs[(size_t)s7 * F + lane];
            acc += v0; acc += v1; acc += v2; acc += v3;
            acc += v4; acc += v5; acc += v6; acc += v7;
        }
        for (; j + 4 <= nv; j += 4) {
            int s0 = __shfl(sv, j + 0), s1 = __shfl(sv, j + 1);
            int s2 = __shfl(sv, j + 2), s3 = __shfl(sv, j + 3);
            float v0 = XWs[(size_t)s0 * F + lane];
            float v1 = XWs[(size_t)s1 * F + lane];
            float v2 = XWs[(size_t)s2 * F + lane];
            float v3 = XWs[(size_t)s3 * F + lane];
            acc += v0; acc += v1; acc += v2; acc += v3;
        }
        for (; j < nv; ++j) {
            int s = __shfl(sv, j);
            acc += XWs[(size_t)s * F + lane];
        }
    }

    if (lane < F) {
        float v = fmaf(acc, dinv[d], b[lane]);
        out[(size_t)d * F + lane] = RELU ? fmaxf(v, 0.0f) : v;
    }
}

extern "C" void kernel_launch(void* const* d_in, const int* in_sizes, int n_in,
                              void* d_out, int out_size, void* d_ws, size_t ws_size,
                              hipStream_t stream) {
    const float* x  = (const float*)d_in[0];
    const int*   ei = (const int*)d_in[1];
    const float* W1 = (const float*)d_in[2];
    const float* b1 = (const float*)d_in[3];
    const float* W2 = (const float*)d_in[4];
    const float* b2 = (const float*)d_in[5];
    const float* W3 = (const float*)d_in[6];
    const float* b3 = (const float*)d_in[7];
    float* out = (float*)d_out;

    const int* src = ei;
    const int* dst = ei + NEDGE;

    char* p = (char*)d_ws;
    auto alloc = [&](size_t bytes) { char* r = p; p += (bytes + 255) & ~size_t(255); return r; };
    unsigned int* bucketed = (unsigned int*)alloc((size_t)NEDGE * 4);
    int*   hist_g     = (int*)  alloc(NBUCKET * 256 * 4);
    int*   base_g     = (int*)  alloc(NBUCKET * 256 * 4);
    int*   colsum     = (int*)  alloc(NBUCKET * 4);
    int*   bucketbase = (int*)  alloc((NBUCKET + 1) * 4);
    int*   rowstart   = (int*)  alloc((NNODE + 1) * 4);
    int*   csr_src    = (int*)  alloc((size_t)NEDGE * 4);
    float* dinv       = (float*)alloc(NNODE * 4);
    float* XWs        = (float*)alloc((size_t)NNODE * 64 * 4 + 256);
    float* H1         = (float*)alloc((size_t)NNODE * 64 * 4);
    float* H2         = (float*)alloc((size_t)NNODE * 64 * 4);

    const int B = 256;
    const int gGemm = (NNODE + 63) / 64;          // 782 (64 rows/block)
    const int gAgg  = (NNODE + 3) / 4;            // 12500

    // CSR build + norm (deterministic-base counting sort)
    k_histA   <<<256, B, 0, stream>>>(dst, hist_g);
    k_scanA1  <<<NBUCKET, B, 0, stream>>>(hist_g, base_g, colsum);
    k_scanA2  <<<1, B, 0, stream>>>(colsum, bucketbase, rowstart);
    k_scatterA<<<256, B, 0, stream>>>(src, dst, base_g, bucketbase, bucketed);
    k_bucketB2<<<NBUCKET, B, 0, stream>>>(bucketed, bucketbase, rowstart, csr_src, dinv);

    // layer 1: 128 -> 64, relu
    k_gemm_prescale<128, 64><<<gGemm, B, 0, stream>>>(x, W1, dinv, XWs);
    k_aggregate<64, true><<<gAgg, B, 0, stream>>>(XWs, rowstart, csr_src, dinv, b1, H1);

    // layer 2: 64 -> 64, relu
    k_gemm_prescale<64, 64><<<gGemm, B, 0, stream>>>(H1, W2, dinv, XWs);
    k_aggregate<64, true><<<gAgg, B, 0, stream>>>(XWs, rowstart, csr_src, dinv, b2, H2);

    // layer 3: 64 -> 40, no act
    k_gemm_prescale<64, 40><<<gGemm, B, 0, stream>>>(H2, W3, dinv, XWs);
    k_aggregate<40, false><<<gAgg, B, 0, stream>>>(XWs, rowstart, csr_src, dinv, b3, out);
}